// Round 10
// baseline (426.085 us; speedup 1.0000x reference)
//
#include <hip/hip_runtime.h>

#define T_STEPS 1024
#define BATCH 128

using u16 = unsigned short;

__device__ __forceinline__ float bf2f(u16 u) {
  union { unsigned int i; float f; } c; c.i = ((unsigned int)u) << 16; return c.f;
}

// ---- fp32 GEMM, bit-exact ascending-k FMA chain per output ----
// Z[m, 0..255] = 2 * sum_k A[m,k]*W[o,k].  Block tile 128x256 (full N), 256 thr,
// 8x16 per-thread micro-tile: 6 b128 LDS reads per k feed 128 FMA
// (vs 4 reads / 64 FMA before) -> shared LDS pipe no longer caps VALU issue.
// XSRC: A comes from x [B,64,T] f32 directly (layer 1, no transpose needed);
// else from S [M,K] bf16-as-u16.  Chain: acc += a*b ascending k (bit-exact).
template <int K, bool XSRC>
__global__ __launch_bounds__(256, 2) void k_gemm(const u16* __restrict__ S,
                                                 const float* __restrict__ W,
                                                 float* __restrict__ Z,
                                                 const float* __restrict__ x) {
  __shared__ float sA[32][136];  // [k][m], 544 B row stride (16B aligned)
  __shared__ float sB[32][264];  // [k][o], 1056 B row stride
  const int m0 = blockIdx.x * 128;
  const int tid = threadIdx.x;
  const int tx = tid & 15, ty = tid >> 4;

  float acc[8][16] = {};
#pragma unroll 1
  for (int kk = 0; kk < K; kk += 32) {
    // ---- stage loads (issued before WAR barrier; overlap prior compute) ----
    float4 bw[8];
    {
      const float* wp = W + (size_t)tid * K + kk;
#pragma unroll
      for (int c = 0; c < 8; ++c) bw[c] = *(const float4*)(wp + c * 4);
    }
    if constexpr (XSRC) {
      const int b = m0 >> 10, t0 = m0 & 1023;
      const int kq = tid >> 3, seg = tid & 7;
      const float* xp = x + ((size_t)b * 64 + kk + kq) * T_STEPS + t0 + seg * 16;
      float4 v0 = *(const float4*)(xp + 0);
      float4 v1 = *(const float4*)(xp + 4);
      float4 v2 = *(const float4*)(xp + 8);
      float4 v3 = *(const float4*)(xp + 12);
      __syncthreads();  // WAR: previous compute done with LDS
      *(float4*)&sA[kq][seg * 16 + 0] = v0;
      *(float4*)&sA[kq][seg * 16 + 4] = v1;
      *(float4*)&sA[kq][seg * 16 + 8] = v2;
      *(float4*)&sA[kq][seg * 16 + 12] = v3;
    } else {
      const int sr = tid >> 1, kh = (tid & 1) * 16;
      const uint4 a0 = *(const uint4*)(S + (size_t)(m0 + sr) * K + kk + kh);
      const uint4 a1 = *(const uint4*)(S + (size_t)(m0 + sr) * K + kk + kh + 8);
      __syncthreads();  // WAR
      const u16* ap = (const u16*)&a0;
#pragma unroll
      for (int j = 0; j < 8; ++j) sA[kh + j][sr] = bf2f(ap[j]);
      const u16* aq = (const u16*)&a1;
#pragma unroll
      for (int j = 0; j < 8; ++j) sA[kh + 8 + j][sr] = bf2f(aq[j]);
    }
    {
      const float* bp = (const float*)&bw[0];
#pragma unroll
      for (int j = 0; j < 32; ++j) sB[j][tid] = bp[j];
    }
    __syncthreads();  // RAW: tile ready
    // ---- compute ----
#pragma unroll 2
    for (int k = 0; k < 32; ++k) {
      float a[8], b[16];
      *(float4*)&a[0] = *(const float4*)&sA[k][ty * 4];
      *(float4*)&a[4] = *(const float4*)&sA[k][64 + ty * 4];
      *(float4*)&b[0] = *(const float4*)&sB[k][tx * 4];
      *(float4*)&b[4] = *(const float4*)&sB[k][64 + tx * 4];
      *(float4*)&b[8] = *(const float4*)&sB[k][128 + tx * 4];
      *(float4*)&b[12] = *(const float4*)&sB[k][192 + tx * 4];
#pragma unroll
      for (int i = 0; i < 8; ++i)
#pragma unroll
        for (int j = 0; j < 16; ++j) acc[i][j] += a[i] * b[j];
    }
  }
  // ---- epilogue ----
#pragma unroll
  for (int i = 0; i < 8; ++i) {
    const int row = m0 + (i < 4 ? ty * 4 + i : 64 + ty * 4 + (i - 4));
    float* zr = Z + (size_t)row * 256;
#pragma unroll
    for (int c = 0; c < 4; ++c) {
      float4 v;
      v.x = 2.f * acc[i][c * 4 + 0];
      v.y = 2.f * acc[i][c * 4 + 1];
      v.z = 2.f * acc[i][c * 4 + 2];
      v.w = 2.f * acc[i][c * 4 + 3];
      *(float4*)(zr + c * 64 + tx * 4) = v;
    }
  }
}

// Layer-3 GEMM: Z3[m, o<11] = 2 * sum_k S[m,k]*W3[o,k], Z3 stride 16.
__global__ __launch_bounds__(256) void k_gemm_out(const u16* __restrict__ S,
                                                  const float* __restrict__ W3,
                                                  float* __restrict__ Z3) {
  __shared__ u16 sS[64 * 264];
  const int m0 = blockIdx.x * 64;
  const int tid = threadIdx.x;
#pragma unroll
  for (int c = 0; c < 8; ++c) {
    const int e = (c * 256 + tid) * 8;
    const int r = e >> 8, k = e & 255;
    *reinterpret_cast<uint4*>(&sS[r * 264 + k]) =
        *reinterpret_cast<const uint4*>(S + (size_t)(m0 + r) * 256 + k);
  }
  __syncthreads();
  const int ml = tid & 63, og = tid >> 6;  // og in 0..3
  const u16* row = &sS[ml * 264];
  const float* w0 = W3 + og * 256;
  const float* w1 = W3 + (og + 4) * 256;
  const float* w2p = W3 + (size_t)(og + 8 < 11 ? og + 8 : og) * 256;
  float acc0 = 0.f, acc1 = 0.f, acc2 = 0.f;
  for (int k = 0; k < 256; ++k) {
    const float sv = bf2f(row[k]);
    acc0 += sv * w0[k];
    acc1 += sv * w1[k];
    acc2 += sv * w2p[k];
  }
  float* zr = Z3 + (size_t)(m0 + ml) * 16;
  zr[og] = 2.f * acc0;
  zr[og + 4] = 2.f * acc1;
  if (og + 8 < 11) zr[og + 8] = 2.f * acc2;
}

// ---- deep-prefetch helpers (static indices after unroll; rule #20) ----
template <int CH, int STR>
__device__ __forceinline__ void load_chunk(const float* __restrict__ zp, int base,
                                           float (&zb)[CH]) {
#pragma unroll
  for (int u = 0; u < CH; ++u) zb[u] = zp[(size_t)(base + u) * STR];
}

// LIF scan with fused axonal delay: Sout[t+d] = spike(t); Sout[t<d] = 0.
__global__ __launch_bounds__(128) void k_scan_delay(const float* __restrict__ Z,
                                                    u16* __restrict__ Sout,
                                                    const int* __restrict__ d) {
  const int b = blockIdx.x >> 1, nh = blockIdx.x & 1;
  const int n = (nh << 7) + threadIdx.x;
  const int del = d[n];
  const float* zp = Z + (size_t)b * T_STEPS * 256 + n;
  u16* sp = Sout + (size_t)b * T_STEPS * 256 + n;
  for (int t = 0; t < del; ++t) sp[(size_t)t * 256] = 0;
  const int tmax = T_STEPS - del;
  float cur = 0.f, vol = 0.f;
  float zA[32], zB[32];
  load_chunk<32, 256>(zp, 0, zA);
  for (int c = 0; c < 32; c += 2) {
    if (c + 1 < 32) load_chunk<32, 256>(zp, (c + 1) * 32, zB);
#pragma unroll
    for (int u = 0; u < 32; ++u) {
      const int t = c * 32 + u;
      cur = 0.75f * cur + zA[u];
      vol = 0.75f * vol + cur;
      const bool s = vol >= 1.25f;
      vol = s ? 0.f : vol;
      if (t < tmax) sp[(size_t)(t + del) * 256] = s ? (u16)0x3F80 : (u16)0;
    }
    if (c + 2 < 32) load_chunk<32, 256>(zp, (c + 2) * 32, zA);
#pragma unroll
    for (int u = 0; u < 32; ++u) {
      const int t = (c + 1) * 32 + u;
      cur = 0.75f * cur + zB[u];
      vol = 0.75f * vol + cur;
      const bool s = vol >= 1.25f;
      vol = s ? 0.f : vol;
      if (t < tmax) sp[(size_t)(t + del) * 256] = s ? (u16)0x3F80 : (u16)0;
    }
  }
}

// Final LIF scan, no delay, writes out[b,o,t] f32.
__global__ __launch_bounds__(64) void k_scan_out(const float* __restrict__ Z3,
                                                 float* __restrict__ out) {
  const int b = blockIdx.x, o = threadIdx.x;
  if (o >= 11) return;
  const float* zp = Z3 + (size_t)b * T_STEPS * 16 + o;
  float* op = out + ((size_t)b * 11 + o) * T_STEPS;
  float cur = 0.f, vol = 0.f;
  float zA[32], zB[32], ob[4];
  load_chunk<32, 16>(zp, 0, zA);
  for (int c = 0; c < 32; c += 2) {
    if (c + 1 < 32) load_chunk<32, 16>(zp, (c + 1) * 32, zB);
#pragma unroll
    for (int u = 0; u < 32; ++u) {
      cur = 0.75f * cur + zA[u];
      vol = 0.75f * vol + cur;
      const bool s = vol >= 1.25f;
      vol = s ? 0.f : vol;
      ob[u & 3] = s ? 1.f : 0.f;
      if ((u & 3) == 3)
        *reinterpret_cast<float4*>(op + c * 32 + (u - 3)) =
            make_float4(ob[0], ob[1], ob[2], ob[3]);
    }
    if (c + 2 < 32) load_chunk<32, 16>(zp, (c + 2) * 32, zA);
#pragma unroll
    for (int u = 0; u < 32; ++u) {
      cur = 0.75f * cur + zB[u];
      vol = 0.75f * vol + cur;
      const bool s = vol >= 1.25f;
      vol = s ? 0.f : vol;
      ob[u & 3] = s ? 1.f : 0.f;
      if ((u & 3) == 3)
        *reinterpret_cast<float4*>(op + (c + 1) * 32 + (u - 3)) =
            make_float4(ob[0], ob[1], ob[2], ob[3]);
    }
  }
}

extern "C" void kernel_launch(void* const* d_in, const int* in_sizes, int n_in,
                              void* d_out, int out_size, void* d_ws, size_t ws_size,
                              hipStream_t stream) {
  const float* x = (const float*)d_in[0];
  const float* w1 = (const float*)d_in[1];
  const float* w2 = (const float*)d_in[2];
  const float* w3 = (const float*)d_in[3];
  const int* d1 = (const int*)d_in[4];
  const int* d2 = (const int*)d_in[5];
  float* out = (float*)d_out;

  const int M = BATCH * T_STEPS;  // 131072
  float* Z = (float*)d_ws;                              // [M,256] f32 = 134 MB
  u16* Sb = (u16*)((char*)d_ws + (size_t)M * 256 * 4);  // [M,256] u16 = 67 MB

  // 1. Z1 = 2 * x @ W1^T   (A read directly from x; no transpose kernel)
  k_gemm<64, true><<<M / 128, 256, 0, stream>>>(Sb, w1, Z, x);
  // 2. LIF scan + delay d1 -> S1
  k_scan_delay<<<BATCH * 2, 128, 0, stream>>>(Z, Sb, d1);
  // 3. Z2 = 2 * S1 @ W2^T
  k_gemm<256, false><<<M / 128, 256, 0, stream>>>(Sb, w2, Z, x);
  // 4. LIF scan + delay d2 -> S2
  k_scan_delay<<<BATCH * 2, 128, 0, stream>>>(Z, Sb, d2);
  // 5. Z3 = 2 * S2 @ W3^T  [M,16(11 used)]
  k_gemm_out<<<M / 64, 256, 0, stream>>>(Sb, w3, Z);
  // 6. LIF scan -> out [B,11,T]
  k_scan_out<<<BATCH, 64, 0, stream>>>(Z, out);
}